// Round 5
// baseline (645.570 us; speedup 1.0000x reference)
//
#include <hip/hip_runtime.h>
#include <hip/hip_bf16.h>
#include <hip/hip_cooperative_groups.h>

namespace cg = cooperative_groups;

#define BATCH 2
#define LSEQ 4096
#define DM 256
#define NS 16
#define BL (BATCH*LSEQ)
#define CHUNK 32
#define NCHUNK (LSEQ/CHUNK)     // 128
#define NCHAIN (BATCH*DM*NS)    // 8192
#define LOG2E 1.4426950408889634f

typedef _Float16 f16x8 __attribute__((ext_vector_type(8)));
typedef _Float16 f16x4 __attribute__((ext_vector_type(4)));
typedef float f32x4 __attribute__((ext_vector_type(4)));

__device__ __forceinline__ float softplus_f(float z){
    return fmaxf(z, 0.0f) + log1pf(__expf(-fabsf(z)));
}
__device__ __forceinline__ float gelu_f(float x){
    float u = 0.7978845608028654f*(x + 0.044715f*x*x*x);
    float e = __builtin_amdgcn_exp2f(2.0f*LOG2E*u);
    float th = 1.0f - 2.0f*__builtin_amdgcn_rcpf(e + 1.0f);
    return 0.5f*x*(1.0f + th);
}

// Final RMSNorm only.
__global__ __launch_bounds__(256) void rmsnorm_k(const float* __restrict__ in,
                                                 float* __restrict__ out){
    int lane = threadIdx.x & 63;
    int wv   = threadIdx.x >> 6;
    int row  = blockIdx.x*4 + wv;
    const float4* rin = (const float4*)(in + (size_t)row*DM);
    float4 v = rin[lane];
    float ss = v.x*v.x + v.y*v.y + v.z*v.z + v.w*v.w;
    #pragma unroll
    for (int off=32; off>=1; off>>=1) ss += __shfl_xor(ss, off, 64);
    float s = rsqrtf(ss*(1.0f/DM) + 1.1920929e-07f);
    float4 o; o.x=v.x*s; o.y=v.y*s; o.z=v.z*s; o.w=v.w*s;
    ((float4*)(out + (size_t)row*DM))[lane] = o;
}

// Pack weights (fp32 -> f16) into MFMA B-fragment order.
__global__ __launch_bounds__(256) void pack_w_k(const float* __restrict__ Wd,
                         const float* __restrict__ WB,
                         const float* __restrict__ WC,
                         const float* __restrict__ Wm,
                         _Float16* __restrict__ pd0, _Float16* __restrict__ pm0,
                         _Float16* __restrict__ pd1, _Float16* __restrict__ pm1){
    int cfg = blockIdx.y;
    int layer = cfg >> 1;
    int isMix = cfg & 1;
    int count = isMix ? 16*8*64 : 18*8*64;
    int t = blockIdx.x*256 + threadIdx.x;
    if (t >= count) return;
    int lane = t & 63;
    int ks   = (t >> 6) & 7;
    int nt16 = t >> 9;
    int col  = nt16*16 + (lane & 15);
    int kb   = ks*32 + ((lane >> 4) << 3);
    const float* Wd_l = Wd + (size_t)layer*DM*DM;
    const float* WB_l = WB + (size_t)layer*DM*NS;
    const float* WC_l = WC + (size_t)layer*DM*NS;
    const float* Wm_l = Wm + (size_t)layer*DM*DM;
    f16x8 v;
    #pragma unroll
    for (int i=0;i<8;++i){
        float s;
        if (isMix)          s = Wm_l[(size_t)(kb+i)*DM + col];
        else if (col < 256) s = Wd_l[(size_t)(kb+i)*DM + col];
        else if (col < 272) s = WB_l[(size_t)(kb+i)*NS + (col-256)];
        else                s = WC_l[(size_t)(kb+i)*NS + (col-272)];
        v[i] = (_Float16)s;
    }
    _Float16* dst = isMix ? (layer ? pm1 : pm0) : (layer ? pd1 : pd0);
    ((f16x8*)dst)[t] = v;
}

// Fused RMSNorm + dtbc GEMM. Block = 32 rows, 576 threads (9 MFMA waves).
// Emits: xn (normalized fp32, for the scan), dt (softplus), Bm, Cm.
__global__ __launch_bounds__(576) void fused_pre(const float* __restrict__ xin,
                          const _Float16* __restrict__ wp,
                          const float* __restrict__ bd,
                          float* __restrict__ xn,
                          float* __restrict__ dt,
                          float* __restrict__ Bm,
                          float* __restrict__ Cm){
    __shared__ _Float16 xs[32*32*8];   // 32 rows x 32 slots x 8 f16 = 16 KB
    int t = threadIdx.x;
    int row0 = blockIdx.x*32;
    if (t < 512){
        int r = t >> 4;          // local row 0..31
        int cb = t & 15;         // float4 column base
        const float4* src = (const float4*)(xin + (size_t)(row0+r)*DM);
        float4 v[4];
        float ss = 0.0f;
        #pragma unroll
        for (int j=0;j<4;++j){
            v[j] = src[cb + 16*j];
            ss += v[j].x*v[j].x + v[j].y*v[j].y + v[j].z*v[j].z + v[j].w*v[j].w;
        }
        ss += __shfl_xor(ss, 1, 64);
        ss += __shfl_xor(ss, 2, 64);
        ss += __shfl_xor(ss, 4, 64);
        ss += __shfl_xor(ss, 8, 64);
        float s = rsqrtf(ss*(1.0f/DM) + 1.1920929e-07f);
        float4* xout = (float4*)(xn + (size_t)(row0+r)*DM);
        #pragma unroll
        for (int j=0;j<4;++j){
            int c4 = cb + 16*j;
            float4 o; o.x=v[j].x*s; o.y=v[j].y*s; o.z=v[j].z*s; o.w=v[j].w*s;
            xout[c4] = o;
            int slot = c4 >> 1;            // k>>3
            int j0   = (c4 & 1)*4;
            f16x4 hv; hv[0]=(_Float16)o.x; hv[1]=(_Float16)o.y;
            hv[2]=(_Float16)o.z; hv[3]=(_Float16)o.w;
            *(f16x4*)&xs[((size_t)r*32 + (slot ^ (r & 7)))*8 + j0] = hv;
        }
    }
    __syncthreads();
    int w    = t >> 6;   // 0..8 = column tile-pair
    int lane = t & 63;
    const f16x8* wpb = (const f16x8*)wp;
    int rl = lane & 15;
    int kg = lane >> 4;
    f32x4 acc[2][2] = {};
    #pragma unroll
    for (int ks=0; ks<8; ++ks){
        int s0 = kg + ks*4;
        f16x8 a0 = *(const f16x8*)&xs[((size_t)(rl     )*32 + (s0 ^ (rl & 7)))*8];
        f16x8 a1 = *(const f16x8*)&xs[((size_t)(rl + 16)*32 + (s0 ^ (rl & 7)))*8];
        f16x8 b0 = wpb[((w*2    )*8 + ks)*64 + lane];
        f16x8 b1 = wpb[((w*2 + 1)*8 + ks)*64 + lane];
        acc[0][0] = __builtin_amdgcn_mfma_f32_16x16x32_f16(a0,b0,acc[0][0],0,0,0);
        acc[0][1] = __builtin_amdgcn_mfma_f32_16x16x32_f16(a0,b1,acc[0][1],0,0,0);
        acc[1][0] = __builtin_amdgcn_mfma_f32_16x16x32_f16(a1,b0,acc[1][0],0,0,0);
        acc[1][1] = __builtin_amdgcn_mfma_f32_16x16x32_f16(a1,b1,acc[1][1],0,0,0);
    }
    int c0 = w*32 + (lane & 15);
    int rb = row0 + ((lane >> 4) << 2);
    if (w < 8){
        float bias0 = bd[c0], bias1 = bd[c0 + 16];
        #pragma unroll
        for (int mi=0; mi<2; ++mi){
            #pragma unroll
            for (int r=0; r<4; ++r){
                int grow = rb + mi*16 + r;
                dt[(size_t)grow*DM + c0]      = softplus_f(acc[mi][0][r] + bias0);
                dt[(size_t)grow*DM + c0 + 16] = softplus_f(acc[mi][1][r] + bias1);
            }
        }
    } else {
        int n = lane & 15;
        #pragma unroll
        for (int mi=0; mi<2; ++mi){
            #pragma unroll
            for (int r=0; r<4; ++r){
                int grow = rb + mi*16 + r;
                Bm[(size_t)grow*NS + n] = acc[mi][0][r];
                Cm[(size_t)grow*NS + n] = acc[mi][1][r];
            }
        }
    }
}

// MFMA GEMM: gelu'd f16 activations @ [256 x 256] + bias -> fp32 out.
__global__ __launch_bounds__(64) void mfma_mix_k(const _Float16* __restrict__ yh,
                          const _Float16* __restrict__ wp,
                          const float* __restrict__ bm,
                          float* __restrict__ out){
    int lane = threadIdx.x;
    int row0 = blockIdx.x*32;
    int nt2  = blockIdx.y;
    const f16x8* ah  = (const f16x8*)yh;
    const f16x8* wpb = (const f16x8*)wp;
    size_t a0i = (size_t)(row0 + (lane & 15))*32 + (lane >> 4);
    f32x4 acc[2][2] = {};
    #pragma unroll
    for (int ks=0; ks<8; ++ks){
        f16x8 a0 = ah[a0i + ks*4];
        f16x8 a1 = ah[a0i + 512 + ks*4];
        f16x8 b0 = wpb[((nt2*2    )*8 + ks)*64 + lane];
        f16x8 b1 = wpb[((nt2*2 + 1)*8 + ks)*64 + lane];
        acc[0][0] = __builtin_amdgcn_mfma_f32_16x16x32_f16(a0,b0,acc[0][0],0,0,0);
        acc[0][1] = __builtin_amdgcn_mfma_f32_16x16x32_f16(a0,b1,acc[0][1],0,0,0);
        acc[1][0] = __builtin_amdgcn_mfma_f32_16x16x32_f16(a1,b0,acc[1][0],0,0,0);
        acc[1][1] = __builtin_amdgcn_mfma_f32_16x16x32_f16(a1,b1,acc[1][1],0,0,0);
    }
    int c0 = nt2*32 + (lane & 15);
    int rb = row0 + ((lane >> 4) << 2);
    float bias0 = bm[c0], bias1 = bm[c0 + 16];
    #pragma unroll
    for (int mi=0; mi<2; ++mi){
        #pragma unroll
        for (int r=0; r<4; ++r){
            int grow = rb + mi*16 + r;
            out[(size_t)grow*DM + c0]      = acc[mi][0][r] + bias0;
            out[(size_t)grow*DM + c0 + 16] = acc[mi][1][r] + bias1;
        }
    }
}

// Fused 3-phase chunked scan (cooperative). grid (NCHUNK, DM/64, BATCH) x 256.
// Thread = (d, n-quad). Phases: chunk summary -> chunk-scan -> replay + yC.
__global__ __launch_bounds__(256) void fused_scan(const float* __restrict__ xn,
                        const float* __restrict__ dt,
                        const float* __restrict__ Bmv,
                        const float* __restrict__ Cmv,
                        const float* __restrict__ A,
                        const float* __restrict__ Dsk,
                        float* __restrict__ cA, float* __restrict__ cB,
                        float* __restrict__ hin,
                        _Float16* __restrict__ yh){
    cg::grid_group grid = cg::this_grid();
    __shared__ float4 bs[CHUNK*4], cs[CHUNK*4];
    int tid = threadIdx.x;
    int c = blockIdx.x, dq = blockIdx.y, b = blockIdx.z;
    int dl = tid >> 2, nq = tid & 3;
    int d  = dq*64 + dl;
    int row0 = b*LSEQ + c*CHUNK;
    if (tid < CHUNK*4){
        bs[tid] = ((const float4*)(Bmv + (size_t)row0*NS))[tid];
        cs[tid] = ((const float4*)(Cmv + (size_t)row0*NS))[tid];
    }
    float4 Alg = ((const float4*)(A + (size_t)d*NS))[nq];
    Alg.x *= LOG2E; Alg.y *= LOG2E; Alg.z *= LOG2E; Alg.w *= LOG2E;
    float dsk = Dsk[d];
    __syncthreads();
    // ---- phase 1: chunk summary ----
    {
        float Ap0=1,Ap1=1,Ap2=1,Ap3=1, Bp0=0,Bp1=0,Bp2=0,Bp3=0;
        #pragma unroll 4
        for (int tt=0; tt<CHUNK; ++tt){
            float dtv = dt[(size_t)(row0+tt)*DM + d];
            float xv  = xn[(size_t)(row0+tt)*DM + d];
            float dtx = dtv*xv;
            float4 bq = bs[tt*4 + nq];
            float a0 = __builtin_amdgcn_exp2f(dtv*Alg.x);
            float a1 = __builtin_amdgcn_exp2f(dtv*Alg.y);
            float a2 = __builtin_amdgcn_exp2f(dtv*Alg.z);
            float a3 = __builtin_amdgcn_exp2f(dtv*Alg.w);
            Ap0 *= a0; Bp0 = fmaf(a0, Bp0, dtx*bq.x);
            Ap1 *= a1; Bp1 = fmaf(a1, Bp1, dtx*bq.y);
            Ap2 *= a2; Bp2 = fmaf(a2, Bp2, dtx*bq.z);
            Ap3 *= a3; Bp3 = fmaf(a3, Bp3, dtx*bq.w);
        }
        size_t base = (size_t)c*NCHAIN + ((size_t)b*DM + d)*NS + nq*4;
        *(float4*)(cA + base) = make_float4(Ap0,Ap1,Ap2,Ap3);
        *(float4*)(cB + base) = make_float4(Bp0,Bp1,Bp2,Bp3);
    }
    grid.sync();
    // ---- phase 2: scan across chunks (first 32 blocks' threads) ----
    {
        int bid = blockIdx.x + gridDim.x*(blockIdx.y + gridDim.y*blockIdx.z);
        int gt = bid*256 + tid;
        if (gt < NCHAIN){
            float h = 0.0f;
            #pragma unroll 8
            for (int cc=0; cc<NCHUNK; ++cc){
                size_t idx = (size_t)cc*NCHAIN + gt;
                hin[idx] = h;
                h = fmaf(cA[idx], h, cB[idx]);
            }
        }
    }
    grid.sync();
    // ---- phase 3: replay with true h_in; y = h.C + D*x; gelu -> f16 ----
    {
        float4 hv = ((const float4*)(hin + (size_t)c*NCHAIN + ((size_t)b*DM + d)*NS))[nq];
        float h0=hv.x, h1=hv.y, h2=hv.z, h3=hv.w;
        #pragma unroll 4
        for (int tt=0; tt<CHUNK; ++tt){
            float dtv = dt[(size_t)(row0+tt)*DM + d];
            float xv  = xn[(size_t)(row0+tt)*DM + d];
            float dtx = dtv*xv;
            float4 bq = bs[tt*4 + nq];
            float4 cq = cs[tt*4 + nq];
            float a0 = __builtin_amdgcn_exp2f(dtv*Alg.x);
            float a1 = __builtin_amdgcn_exp2f(dtv*Alg.y);
            float a2 = __builtin_amdgcn_exp2f(dtv*Alg.z);
            float a3 = __builtin_amdgcn_exp2f(dtv*Alg.w);
            h0 = fmaf(a0, h0, dtx*bq.x);
            h1 = fmaf(a1, h1, dtx*bq.y);
            h2 = fmaf(a2, h2, dtx*bq.z);
            h3 = fmaf(a3, h3, dtx*bq.w);
            float p = fmaf(h0, cq.x, fmaf(h1, cq.y, fmaf(h2, cq.z, h3*cq.w)));
            p += __shfl_xor(p, 1, 64);
            p += __shfl_xor(p, 2, 64);
            if (nq == 0){
                float yv = p + dsk*xv;
                yh[(size_t)(row0+tt)*DM + d] = (_Float16)gelu_f(yv);
            }
        }
    }
}

extern "C" void kernel_launch(void* const* d_in, const int* in_sizes, int n_in,
                              void* d_out, int out_size, void* d_ws, size_t ws_size,
                              hipStream_t stream) {
    const float* x  = (const float*)d_in[0];
    const float* A  = (const float*)d_in[1];
    const float* Wd = (const float*)d_in[2];
    const float* bd = (const float*)d_in[3];
    const float* WB = (const float*)d_in[4];
    const float* WC = (const float*)d_in[5];
    const float* Ds = (const float*)d_in[6];
    const float* Wm = (const float*)d_in[7];
    const float* bm = (const float*)d_in[8];
    float* out = (float*)d_out;

    const size_t BSZ = (size_t)BL*DM;          // 2,097,152 floats
    const size_t CH  = (size_t)NCHUNK*NCHAIN;  // 1,048,576 floats
    float* ws  = (float*)d_ws;
    float* b0  = ws;                 // xn
    float* b1  = b0  + BSZ;          // dt
    float* b2  = b1  + BSZ;          // mix out / layer activations
    float* Bmb = b2  + BSZ;
    float* Cmb = Bmb + (size_t)BL*NS;
    float* cA  = Cmb + (size_t)BL*NS;
    float* cB  = cA  + CH;
    float* hin = cB  + CH;
    _Float16* packs = (_Float16*)(hin + CH);
    _Float16* pd0 = packs;
    _Float16* pd1 = pd0 + 73728;
    _Float16* pm0 = pd1 + 73728;
    _Float16* pm1 = pm0 + 65536;
    _Float16* yh = (_Float16*)cB;   // aliased: cB dead after phase 2

    dim3 gscan(NCHUNK, DM/64, BATCH);
    dim3 gmx(BL/32, 8);

    pack_w_k<<<dim3(36,4), 256, 0, stream>>>(Wd, WB, WC, Wm, pd0, pm0, pd1, pm1);

    const float* A1  = A  + (size_t)DM*NS;
    const float* bd1 = bd + DM;
    const float* Ds1 = Ds + DM;
    const float* bm1 = bm + DM;

    // ---- layer 0 ----
    fused_pre<<<BL/32, 576, 0, stream>>>(x, pd0, bd, b0, b1, Bmb, Cmb);
    {
        const float *a0=b0, *a1=b1, *a2=Bmb, *a3=Cmb, *a4=A, *a5=Ds;
        float *a6=cA, *a7=cB, *a8=hin; _Float16 *a9=yh;
        void* args[] = {&a0,&a1,&a2,&a3,&a4,&a5,&a6,&a7,&a8,&a9};
        hipLaunchCooperativeKernel((const void*)fused_scan, gscan, dim3(256),
                                   args, 0, stream);
    }
    mfma_mix_k<<<gmx, 64, 0, stream>>>(yh, pm0, bm, b2);

    // ---- layer 1 ----
    fused_pre<<<BL/32, 576, 0, stream>>>(b2, pd1, bd1, b0, b1, Bmb, Cmb);
    {
        const float *a0=b0, *a1=b1, *a2=Bmb, *a3=Cmb, *a4=A1, *a5=Ds1;
        float *a6=cA, *a7=cB, *a8=hin; _Float16 *a9=yh;
        void* args[] = {&a0,&a1,&a2,&a3,&a4,&a5,&a6,&a7,&a8,&a9};
        hipLaunchCooperativeKernel((const void*)fused_scan, gscan, dim3(256),
                                   args, 0, stream);
    }
    mfma_mix_k<<<gmx, 64, 0, stream>>>(yh, pm1, bm1, b2);

    // ---- final norm ----
    rmsnorm_k<<<BL/4, 256, 0, stream>>>(b2, out);
}

// Round 6
// 182.384 us; speedup vs baseline: 3.5396x; 3.5396x over previous
//
#include <hip/hip_runtime.h>
#include <hip/hip_bf16.h>

#define BATCH 2
#define LSEQ 4096
#define DM 256
#define NS 16
#define BL (BATCH*LSEQ)
#define CHUNK 32
#define NCHUNK (LSEQ/CHUNK)     // 128
#define NCHAIN (BATCH*DM*NS)    // 8192
#define SEG 8                   // threads per chain in scan_p2
#define CPS (NCHUNK/SEG)        // chunks per segment = 16
#define MS_STRIDE 260           // fp32 LDS row stride (16B aligned, conflict-light)
#define LOG2E 1.4426950408889634f

typedef _Float16 f16x8 __attribute__((ext_vector_type(8)));
typedef _Float16 f16x4 __attribute__((ext_vector_type(4)));
typedef float f32x4 __attribute__((ext_vector_type(4)));

__device__ __forceinline__ float softplus_f(float z){
    return fmaxf(z, 0.0f) + log1pf(__expf(-fabsf(z)));
}
__device__ __forceinline__ float gelu_f(float x){
    float u = 0.7978845608028654f*(x + 0.044715f*x*x*x);
    float e = __builtin_amdgcn_exp2f(2.0f*LOG2E*u);
    float th = 1.0f - 2.0f*__builtin_amdgcn_rcpf(e + 1.0f);
    return 0.5f*x*(1.0f + th);
}

// Pack weights (fp32 -> f16) into MFMA B-fragment order.
__global__ __launch_bounds__(256) void pack_w_k(const float* __restrict__ Wd,
                         const float* __restrict__ WB,
                         const float* __restrict__ WC,
                         const float* __restrict__ Wm,
                         _Float16* __restrict__ pd0, _Float16* __restrict__ pm0,
                         _Float16* __restrict__ pd1, _Float16* __restrict__ pm1){
    int cfg = blockIdx.y;
    int layer = cfg >> 1;
    int isMix = cfg & 1;
    int count = isMix ? 16*8*64 : 18*8*64;
    int t = blockIdx.x*256 + threadIdx.x;
    if (t >= count) return;
    int lane = t & 63;
    int ks   = (t >> 6) & 7;
    int nt16 = t >> 9;
    int col  = nt16*16 + (lane & 15);
    int kb   = ks*32 + ((lane >> 4) << 3);
    const float* Wd_l = Wd + (size_t)layer*DM*DM;
    const float* WB_l = WB + (size_t)layer*DM*NS;
    const float* WC_l = WC + (size_t)layer*DM*NS;
    const float* Wm_l = Wm + (size_t)layer*DM*DM;
    f16x8 v;
    #pragma unroll
    for (int i=0;i<8;++i){
        float s;
        if (isMix)          s = Wm_l[(size_t)(kb+i)*DM + col];
        else if (col < 256) s = Wd_l[(size_t)(kb+i)*DM + col];
        else if (col < 272) s = WB_l[(size_t)(kb+i)*NS + (col-256)];
        else                s = WC_l[(size_t)(kb+i)*NS + (col-272)];
        v[i] = (_Float16)s;
    }
    _Float16* dst = isMix ? (layer ? pm1 : pm0) : (layer ? pd1 : pd0);
    ((f16x8*)dst)[t] = v;
}

// Fused RMSNorm + dtbc GEMM. Block = 32 rows, 576 threads (9 MFMA waves).
__global__ __launch_bounds__(576) void fused_pre(const float* __restrict__ xin,
                          const _Float16* __restrict__ wp,
                          const float* __restrict__ bd,
                          float* __restrict__ xn,
                          float* __restrict__ dt,
                          float* __restrict__ Bm,
                          float* __restrict__ Cm){
    __shared__ _Float16 xs[32*32*8];   // 16 KB
    int t = threadIdx.x;
    int row0 = blockIdx.x*32;
    if (t < 512){
        int r = t >> 4;
        int cb = t & 15;
        const float4* src = (const float4*)(xin + (size_t)(row0+r)*DM);
        float4 v[4];
        float ss = 0.0f;
        #pragma unroll
        for (int j=0;j<4;++j){
            v[j] = src[cb + 16*j];
            ss += v[j].x*v[j].x + v[j].y*v[j].y + v[j].z*v[j].z + v[j].w*v[j].w;
        }
        ss += __shfl_xor(ss, 1, 64);
        ss += __shfl_xor(ss, 2, 64);
        ss += __shfl_xor(ss, 4, 64);
        ss += __shfl_xor(ss, 8, 64);
        float s = rsqrtf(ss*(1.0f/DM) + 1.1920929e-07f);
        float4* xout = (float4*)(xn + (size_t)(row0+r)*DM);
        #pragma unroll
        for (int j=0;j<4;++j){
            int c4 = cb + 16*j;
            float4 o; o.x=v[j].x*s; o.y=v[j].y*s; o.z=v[j].z*s; o.w=v[j].w*s;
            xout[c4] = o;
            int slot = c4 >> 1;
            int j0   = (c4 & 1)*4;
            f16x4 hv; hv[0]=(_Float16)o.x; hv[1]=(_Float16)o.y;
            hv[2]=(_Float16)o.z; hv[3]=(_Float16)o.w;
            *(f16x4*)&xs[((size_t)r*32 + (slot ^ (r & 7)))*8 + j0] = hv;
        }
    }
    __syncthreads();
    int w    = t >> 6;
    int lane = t & 63;
    const f16x8* wpb = (const f16x8*)wp;
    int rl = lane & 15;
    int kg = lane >> 4;
    f32x4 acc[2][2] = {};
    #pragma unroll
    for (int ks=0; ks<8; ++ks){
        int s0 = kg + ks*4;
        f16x8 a0 = *(const f16x8*)&xs[((size_t)(rl     )*32 + (s0 ^ (rl & 7)))*8];
        f16x8 a1 = *(const f16x8*)&xs[((size_t)(rl + 16)*32 + (s0 ^ (rl & 7)))*8];
        f16x8 b0 = wpb[((w*2    )*8 + ks)*64 + lane];
        f16x8 b1 = wpb[((w*2 + 1)*8 + ks)*64 + lane];
        acc[0][0] = __builtin_amdgcn_mfma_f32_16x16x32_f16(a0,b0,acc[0][0],0,0,0);
        acc[0][1] = __builtin_amdgcn_mfma_f32_16x16x32_f16(a0,b1,acc[0][1],0,0,0);
        acc[1][0] = __builtin_amdgcn_mfma_f32_16x16x32_f16(a1,b0,acc[1][0],0,0,0);
        acc[1][1] = __builtin_amdgcn_mfma_f32_16x16x32_f16(a1,b1,acc[1][1],0,0,0);
    }
    int c0 = w*32 + (lane & 15);
    int rb = row0 + ((lane >> 4) << 2);
    if (w < 8){
        float bias0 = bd[c0], bias1 = bd[c0 + 16];
        #pragma unroll
        for (int mi=0; mi<2; ++mi){
            #pragma unroll
            for (int r=0; r<4; ++r){
                int grow = rb + mi*16 + r;
                dt[(size_t)grow*DM + c0]      = softplus_f(acc[mi][0][r] + bias0);
                dt[(size_t)grow*DM + c0 + 16] = softplus_f(acc[mi][1][r] + bias1);
            }
        }
    } else {
        int n = lane & 15;
        #pragma unroll
        for (int mi=0; mi<2; ++mi){
            #pragma unroll
            for (int r=0; r<4; ++r){
                int grow = rb + mi*16 + r;
                Bm[(size_t)grow*NS + n] = acc[mi][0][r];
                Cm[(size_t)grow*NS + n] = acc[mi][1][r];
            }
        }
    }
}

// Fused mix-GEMM + RMSNorm + next-layer dtbc-GEMM. 576 threads, 32 rows/block.
__global__ __launch_bounds__(576) void fused_mid(const _Float16* __restrict__ yh,
                          const _Float16* __restrict__ wpm,
                          const float* __restrict__ bm,
                          const _Float16* __restrict__ wpd,
                          const float* __restrict__ bd,
                          float* __restrict__ xn,
                          float* __restrict__ dt,
                          float* __restrict__ Bm,
                          float* __restrict__ Cm){
    __shared__ float ms[32*MS_STRIDE];   // 32.5 KB mix output
    __shared__ _Float16 xs[32*32*8];     // 16 KB f16 fragments
    int t = threadIdx.x;
    int w = t >> 6, lane = t & 63;
    int row0 = blockIdx.x*32;
    // ---- phase A: mix GEMM (waves 0..7) -> LDS ----
    if (w < 8){
        const f16x8* ah  = (const f16x8*)yh;
        const f16x8* wpb = (const f16x8*)wpm;
        size_t a0i = (size_t)(row0 + (lane & 15))*32 + (lane >> 4);
        f32x4 acc[2][2] = {};
        #pragma unroll
        for (int ks=0; ks<8; ++ks){
            f16x8 a0 = ah[a0i + ks*4];
            f16x8 a1 = ah[a0i + 512 + ks*4];
            f16x8 b0 = wpb[((w*2    )*8 + ks)*64 + lane];
            f16x8 b1 = wpb[((w*2 + 1)*8 + ks)*64 + lane];
            acc[0][0] = __builtin_amdgcn_mfma_f32_16x16x32_f16(a0,b0,acc[0][0],0,0,0);
            acc[0][1] = __builtin_amdgcn_mfma_f32_16x16x32_f16(a0,b1,acc[0][1],0,0,0);
            acc[1][0] = __builtin_amdgcn_mfma_f32_16x16x32_f16(a1,b0,acc[1][0],0,0,0);
            acc[1][1] = __builtin_amdgcn_mfma_f32_16x16x32_f16(a1,b1,acc[1][1],0,0,0);
        }
        int c0 = w*32 + (lane & 15);
        int rb = (lane >> 4) << 2;
        float bias0 = bm[c0], bias1 = bm[c0 + 16];
        #pragma unroll
        for (int mi=0; mi<2; ++mi){
            #pragma unroll
            for (int r=0; r<4; ++r){
                int lr = rb + mi*16 + r;
                ms[lr*MS_STRIDE + c0]      = acc[mi][0][r] + bias0;
                ms[lr*MS_STRIDE + c0 + 16] = acc[mi][1][r] + bias1;
            }
        }
    }
    __syncthreads();
    // ---- phase B: RMSNorm rows from LDS -> xn global + xs f16 ----
    if (t < 512){
        int r = t >> 4;
        int cb = t & 15;
        float4 v[4];
        float ss = 0.0f;
        #pragma unroll
        for (int j=0;j<4;++j){
            v[j] = *(const float4*)&ms[r*MS_STRIDE + (cb + 16*j)*4];
            ss += v[j].x*v[j].x + v[j].y*v[j].y + v[j].z*v[j].z + v[j].w*v[j].w;
        }
        ss += __shfl_xor(ss, 1, 64);
        ss += __shfl_xor(ss, 2, 64);
        ss += __shfl_xor(ss, 4, 64);
        ss += __shfl_xor(ss, 8, 64);
        float s = rsqrtf(ss*(1.0f/DM) + 1.1920929e-07f);
        float4* xout = (float4*)(xn + (size_t)(row0+r)*DM);
        #pragma unroll
        for (int j=0;j<4;++j){
            int c4 = cb + 16*j;
            float4 o; o.x=v[j].x*s; o.y=v[j].y*s; o.z=v[j].z*s; o.w=v[j].w*s;
            xout[c4] = o;
            int slot = c4 >> 1;
            int j0   = (c4 & 1)*4;
            f16x4 hv; hv[0]=(_Float16)o.x; hv[1]=(_Float16)o.y;
            hv[2]=(_Float16)o.z; hv[3]=(_Float16)o.w;
            *(f16x4*)&xs[((size_t)r*32 + (slot ^ (r & 7)))*8 + j0] = hv;
        }
    }
    __syncthreads();
    // ---- phase C: dtbc GEMM (all 9 waves) ----
    {
        const f16x8* wpb = (const f16x8*)wpd;
        int rl = lane & 15;
        int kg = lane >> 4;
        f32x4 acc[2][2] = {};
        #pragma unroll
        for (int ks=0; ks<8; ++ks){
            int s0 = kg + ks*4;
            f16x8 a0 = *(const f16x8*)&xs[((size_t)(rl     )*32 + (s0 ^ (rl & 7)))*8];
            f16x8 a1 = *(const f16x8*)&xs[((size_t)(rl + 16)*32 + (s0 ^ (rl & 7)))*8];
            f16x8 b0 = wpb[((w*2    )*8 + ks)*64 + lane];
            f16x8 b1 = wpb[((w*2 + 1)*8 + ks)*64 + lane];
            acc[0][0] = __builtin_amdgcn_mfma_f32_16x16x32_f16(a0,b0,acc[0][0],0,0,0);
            acc[0][1] = __builtin_amdgcn_mfma_f32_16x16x32_f16(a0,b1,acc[0][1],0,0,0);
            acc[1][0] = __builtin_amdgcn_mfma_f32_16x16x32_f16(a1,b0,acc[1][0],0,0,0);
            acc[1][1] = __builtin_amdgcn_mfma_f32_16x16x32_f16(a1,b1,acc[1][1],0,0,0);
        }
        int c0 = w*32 + (lane & 15);
        int rb = row0 + ((lane >> 4) << 2);
        if (w < 8){
            float bias0 = bd[c0], bias1 = bd[c0 + 16];
            #pragma unroll
            for (int mi=0; mi<2; ++mi){
                #pragma unroll
                for (int r=0; r<4; ++r){
                    int grow = rb + mi*16 + r;
                    dt[(size_t)grow*DM + c0]      = softplus_f(acc[mi][0][r] + bias0);
                    dt[(size_t)grow*DM + c0 + 16] = softplus_f(acc[mi][1][r] + bias1);
                }
            }
        } else {
            int n = lane & 15;
            #pragma unroll
            for (int mi=0; mi<2; ++mi){
                #pragma unroll
                for (int r=0; r<4; ++r){
                    int grow = rb + mi*16 + r;
                    Bm[(size_t)grow*NS + n] = acc[mi][0][r];
                    Cm[(size_t)grow*NS + n] = acc[mi][1][r];
                }
            }
        }
    }
}

// Fused final mix-GEMM + final RMSNorm -> out. 512 threads, 32 rows/block.
__global__ __launch_bounds__(512) void fused_out(const _Float16* __restrict__ yh,
                          const _Float16* __restrict__ wpm,
                          const float* __restrict__ bm,
                          float* __restrict__ out){
    __shared__ float ms[32*MS_STRIDE];
    int t = threadIdx.x;
    int w = t >> 6, lane = t & 63;
    int row0 = blockIdx.x*32;
    {
        const f16x8* ah  = (const f16x8*)yh;
        const f16x8* wpb = (const f16x8*)wpm;
        size_t a0i = (size_t)(row0 + (lane & 15))*32 + (lane >> 4);
        f32x4 acc[2][2] = {};
        #pragma unroll
        for (int ks=0; ks<8; ++ks){
            f16x8 a0 = ah[a0i + ks*4];
            f16x8 a1 = ah[a0i + 512 + ks*4];
            f16x8 b0 = wpb[((w*2    )*8 + ks)*64 + lane];
            f16x8 b1 = wpb[((w*2 + 1)*8 + ks)*64 + lane];
            acc[0][0] = __builtin_amdgcn_mfma_f32_16x16x32_f16(a0,b0,acc[0][0],0,0,0);
            acc[0][1] = __builtin_amdgcn_mfma_f32_16x16x32_f16(a0,b1,acc[0][1],0,0,0);
            acc[1][0] = __builtin_amdgcn_mfma_f32_16x16x32_f16(a1,b0,acc[1][0],0,0,0);
            acc[1][1] = __builtin_amdgcn_mfma_f32_16x16x32_f16(a1,b1,acc[1][1],0,0,0);
        }
        int c0 = w*32 + (lane & 15);
        int rb = (lane >> 4) << 2;
        float bias0 = bm[c0], bias1 = bm[c0 + 16];
        #pragma unroll
        for (int mi=0; mi<2; ++mi){
            #pragma unroll
            for (int r=0; r<4; ++r){
                int lr = rb + mi*16 + r;
                ms[lr*MS_STRIDE + c0]      = acc[mi][0][r] + bias0;
                ms[lr*MS_STRIDE + c0 + 16] = acc[mi][1][r] + bias1;
            }
        }
    }
    __syncthreads();
    {
        int r = t >> 4;
        int cb = t & 15;
        float4 v[4];
        float ss = 0.0f;
        #pragma unroll
        for (int j=0;j<4;++j){
            v[j] = *(const float4*)&ms[r*MS_STRIDE + (cb + 16*j)*4];
            ss += v[j].x*v[j].x + v[j].y*v[j].y + v[j].z*v[j].z + v[j].w*v[j].w;
        }
        ss += __shfl_xor(ss, 1, 64);
        ss += __shfl_xor(ss, 2, 64);
        ss += __shfl_xor(ss, 4, 64);
        ss += __shfl_xor(ss, 8, 64);
        float s = rsqrtf(ss*(1.0f/DM) + 1.1920929e-07f);
        float4* xout = (float4*)(out + (size_t)(row0+r)*DM);
        #pragma unroll
        for (int j=0;j<4;++j){
            float4 o = v[j];
            o.x*=s; o.y*=s; o.z*=s; o.w*=s;
            xout[cb + 16*j] = o;
        }
    }
}

// Scan phase 1: 256 threads = 64 d's x 4 n-quads. grid (NCHUNK, DM/64, BATCH).
__global__ __launch_bounds__(256) void scan_p1(const float* __restrict__ xn,
                        const float* __restrict__ dt,
                        const float* __restrict__ Bmv,
                        const float* __restrict__ A,
                        float* __restrict__ cA, float* __restrict__ cB){
    __shared__ float4 bs[CHUNK*4];
    int tid = threadIdx.x;
    int c = blockIdx.x, dq = blockIdx.y, b = blockIdx.z;
    int dl = tid >> 2, nq = tid & 3;
    int d  = dq*64 + dl;
    int row0 = b*LSEQ + c*CHUNK;
    if (tid < CHUNK*4) bs[tid] = ((const float4*)(Bmv + (size_t)row0*NS))[tid];
    float4 Alg = ((const float4*)(A + (size_t)d*NS))[nq];
    Alg.x *= LOG2E; Alg.y *= LOG2E; Alg.z *= LOG2E; Alg.w *= LOG2E;
    __syncthreads();
    float Ap0=1,Ap1=1,Ap2=1,Ap3=1, Bp0=0,Bp1=0,Bp2=0,Bp3=0;
    #pragma unroll 4
    for (int tt=0; tt<CHUNK; ++tt){
        float dtv = dt[(size_t)(row0+tt)*DM + d];
        float xv  = xn[(size_t)(row0+tt)*DM + d];
        float dtx = dtv*xv;
        float4 bq = bs[tt*4 + nq];
        float a0 = __builtin_amdgcn_exp2f(dtv*Alg.x);
        float a1 = __builtin_amdgcn_exp2f(dtv*Alg.y);
        float a2 = __builtin_amdgcn_exp2f(dtv*Alg.z);
        float a3 = __builtin_amdgcn_exp2f(dtv*Alg.w);
        Ap0 *= a0; Bp0 = fmaf(a0, Bp0, dtx*bq.x);
        Ap1 *= a1; Bp1 = fmaf(a1, Bp1, dtx*bq.y);
        Ap2 *= a2; Bp2 = fmaf(a2, Bp2, dtx*bq.z);
        Ap3 *= a3; Bp3 = fmaf(a3, Bp3, dtx*bq.w);
    }
    size_t base = (size_t)c*NCHAIN + ((size_t)b*DM + d)*NS + nq*4;
    *(float4*)(cA + base) = make_float4(Ap0,Ap1,Ap2,Ap3);
    *(float4*)(cB + base) = make_float4(Bp0,Bp1,Bp2,Bp3);
}

// Phase 2: segmented affine scan across chunks. 8 threads/chain.
// grid: NCHAIN*SEG/256 = 256 blocks.
__global__ __launch_bounds__(256) void scan_p2(const float* __restrict__ cA,
                        const float* __restrict__ cB,
                        float* __restrict__ hin){
    int gt = blockIdx.x*256 + threadIdx.x;
    int chain = gt >> 3;
    int seg   = gt & 7;
    int c0 = seg*CPS;
    float Ac = 1.0f, Bc = 0.0f;
    #pragma unroll 4
    for (int i=0;i<CPS;++i){
        size_t idx = (size_t)(c0+i)*NCHAIN + chain;
        float a = cA[idx], b = cB[idx];
        Bc = fmaf(a, Bc, b);
        Ac *= a;
    }
    // inclusive affine scan over the 8 segment-lanes
    #pragma unroll
    for (int dlt=1; dlt<8; dlt<<=1){
        float Apv = __shfl_up(Ac, dlt, 64);
        float Bpv = __shfl_up(Bc, dlt, 64);
        if (seg >= dlt){
            Bc = fmaf(Ac, Bpv, Bc);
            Ac *= Apv;
        }
    }
    float hprev = __shfl_up(Bc, 1, 64);
    float h = (seg == 0) ? 0.0f : hprev;
    #pragma unroll 4
    for (int i=0;i<CPS;++i){
        size_t idx = (size_t)(c0+i)*NCHAIN + chain;
        hin[idx] = h;
        h = fmaf(cA[idx], h, cB[idx]);
    }
}

// Phase 3: replay with correct h_in; y = sum_n h*C + D_skip*x; emit gelu(y) f16.
__global__ __launch_bounds__(256) void scan_p3(const float* __restrict__ xn,
                        const float* __restrict__ dt,
                        const float* __restrict__ Bmv,
                        const float* __restrict__ Cmv,
                        const float* __restrict__ A,
                        const float* __restrict__ Dsk,
                        const float* __restrict__ hin,
                        _Float16* __restrict__ yh){
    __shared__ float4 bs[CHUNK*4], cs[CHUNK*4];
    int tid = threadIdx.x;
    int c = blockIdx.x, dq = blockIdx.y, b = blockIdx.z;
    int dl = tid >> 2, nq = tid & 3;
    int d  = dq*64 + dl;
    int row0 = b*LSEQ + c*CHUNK;
    if (tid < CHUNK*4){
        bs[tid] = ((const float4*)(Bmv + (size_t)row0*NS))[tid];
        cs[tid] = ((const float4*)(Cmv + (size_t)row0*NS))[tid];
    }
    float4 Alg = ((const float4*)(A + (size_t)d*NS))[nq];
    Alg.x *= LOG2E; Alg.y *= LOG2E; Alg.z *= LOG2E; Alg.w *= LOG2E;
    float dsk = Dsk[d];
    float4 hv = ((const float4*)(hin + (size_t)c*NCHAIN + ((size_t)b*DM + d)*NS))[nq];
    float h0=hv.x, h1=hv.y, h2=hv.z, h3=hv.w;
    __syncthreads();
    #pragma unroll 4
    for (int tt=0; tt<CHUNK; ++tt){
        float dtv = dt[(size_t)(row0+tt)*DM + d];
        float xv  = xn[(size_t)(row0+tt)*DM + d];
        float dtx = dtv*xv;
        float4 bq = bs[tt*4 + nq];
        float4 cq = cs[tt*4 + nq];
        float a0 = __builtin_amdgcn_exp2f(dtv*Alg.x);
        float a1 = __builtin_amdgcn_exp2f(dtv*Alg.y);
        float a2 = __builtin_amdgcn_exp2f(dtv*Alg.z);
        float a3 = __builtin_amdgcn_exp2f(dtv*Alg.w);
        h0 = fmaf(a0, h0, dtx*bq.x);
        h1 = fmaf(a1, h1, dtx*bq.y);
        h2 = fmaf(a2, h2, dtx*bq.z);
        h3 = fmaf(a3, h3, dtx*bq.w);
        float p = fmaf(h0, cq.x, fmaf(h1, cq.y, fmaf(h2, cq.z, h3*cq.w)));
        p += __shfl_xor(p, 1, 64);
        p += __shfl_xor(p, 2, 64);
        if (nq == 0){
            float yv = p + dsk*xv;
            yh[(size_t)(row0+tt)*DM + d] = (_Float16)gelu_f(yv);
        }
    }
}

extern "C" void kernel_launch(void* const* d_in, const int* in_sizes, int n_in,
                              void* d_out, int out_size, void* d_ws, size_t ws_size,
                              hipStream_t stream) {
    const float* x  = (const float*)d_in[0];
    const float* A  = (const float*)d_in[1];
    const float* Wd = (const float*)d_in[2];
    const float* bd = (const float*)d_in[3];
    const float* WB = (const float*)d_in[4];
    const float* WC = (const float*)d_in[5];
    const float* Ds = (const float*)d_in[6];
    const float* Wm = (const float*)d_in[7];
    const float* bm = (const float*)d_in[8];
    float* out = (float*)d_out;

    const size_t BSZ = (size_t)BL*DM;          // 2,097,152 floats
    const size_t CH  = (size_t)NCHUNK*NCHAIN;  // 1,048,576 floats
    float* ws  = (float*)d_ws;
    float* b0  = ws;                 // xn
    float* b1  = b0  + BSZ;          // dt
    float* b2  = b1  + BSZ;          // (spare)
    float* Bmb = b2  + BSZ;
    float* Cmb = Bmb + (size_t)BL*NS;
    float* cA  = Cmb + (size_t)BL*NS;
    float* cB  = cA  + CH;
    float* hin = cB  + CH;
    _Float16* packs = (_Float16*)(hin + CH);
    _Float16* pd0 = packs;
    _Float16* pd1 = pd0 + 73728;
    _Float16* pm0 = pd1 + 73728;
    _Float16* pm1 = pm0 + 65536;
    _Float16* yh = (_Float16*)cB;   // aliased: cB dead after scan_p2

    dim3 gscan(NCHUNK, DM/64, BATCH);

    pack_w_k<<<dim3(36,4), 256, 0, stream>>>(Wd, WB, WC, Wm, pd0, pm0, pd1, pm1);

    const float* A1  = A  + (size_t)DM*NS;
    const float* bd1 = bd + DM;
    const float* Ds1 = Ds + DM;
    const float* bm1 = bm + DM;

    // ---- layer 0 ----
    fused_pre<<<BL/32, 576, 0, stream>>>(x, pd0, bd, b0, b1, Bmb, Cmb);
    scan_p1<<<gscan, 256, 0, stream>>>(b0, b1, Bmb, A, cA, cB);
    scan_p2<<<NCHAIN*SEG/256, 256, 0, stream>>>(cA, cB, hin);
    scan_p3<<<gscan, 256, 0, stream>>>(b0, b1, Bmb, Cmb, A, Ds, hin, yh);
    // ---- mix(L0) + rmsnorm + dtbc(L1) ----
    fused_mid<<<BL/32, 576, 0, stream>>>(yh, pm0, bm, pd1, bd1, b0, b1, Bmb, Cmb);
    // ---- layer 1 scan ----
    scan_p1<<<gscan, 256, 0, stream>>>(b0, b1, Bmb, A1, cA, cB);
    scan_p2<<<NCHAIN*SEG/256, 256, 0, stream>>>(cA, cB, hin);
    scan_p3<<<gscan, 256, 0, stream>>>(b0, b1, Bmb, Cmb, A1, Ds1, hin, yh);
    // ---- mix(L1) + final rmsnorm ----
    fused_out<<<BL/32, 512, 0, stream>>>(yh, pm1, bm1, out);
}